// Round 11
// baseline (845.118 us; speedup 1.0000x reference)
//
#include <hip/hip_runtime.h>
#include <hip/hip_bf16.h>

typedef unsigned short ushort_t;
typedef unsigned int   uint_t;
typedef __attribute__((ext_vector_type(8))) short bf8;
typedef __attribute__((ext_vector_type(4))) float f32x4;

constexpr int N = 50000;
constexpr int E = 600000;
constexpr int D = 128;
constexpr int L = 2;

// fused layer tiling (R8/R9-proven): 80 output rows/tile + 16 lookback rows
// recomputed (decay |g*A|^16 ~ 2e-8).  Two bf16 LDS planes SCA/SCB[96][136];
// h overwrites SCA rows 16..95 in place.  LDS 52864 B.
constexpr int RB   = 80;
constexpr int RBLK = N / RB;   // 625 tiles
constexpr int LOOK = 16;
constexpr int CSTR = 136;
constexpr int CROWS = RB + LOOK;   // 96

// persistent-block grids (software grid barrier -> co-residency REQUIRED):
// k_pre: 512 blocks, 0 LDS, launch_bounds(256,4) -> capacity >= 1024 (2x).
// k_layers: 416 blocks, 52.9KB LDS -> 2 blocks/CU ALWAYS fit (105.8<=160KB)
//           -> capacity >= 512 >= 416.
constexpr int PREB = 512;
constexpr int PRET = PREB * 256;        // 131072 threads
constexpr int PREW = PREB * 4;          // 2048 waves
constexpr int LBLK = 416;

constexpr size_t CAST_TBL = 3276800;                               // table f2 elems
constexpr size_t CAST_W   = CAST_TBL + (size_t)L * 256 * 128
                                     + (size_t)L * 128 * 128;      // 3,375,104
constexpr size_t CAST_H   = CAST_W + E;                            // + hist
constexpr size_t CAST_TOT = CAST_H + N;                            // + invp

__device__ __forceinline__ float us2f(ushort_t u) {
    union { uint_t i; float f; } c; c.i = (uint_t)u << 16; return c.f;
}
__device__ __forceinline__ float u2f(uint_t u) {
    union { uint_t i; float f; } c; c.i = u; return c.f;
}
__device__ __forceinline__ ushort_t f2us(float f) {
    __hip_bfloat16 b = __float2bfloat16(f);
    return *(ushort_t*)&b;
}

// ---------------------------------------------------------------------------
// Software grid barrier (sense-reversal, device-scope atomics).  bar[0]=count,
// bar[1]=generation; both zeroed by the pre-kernel memset.  Requires all
// gridDim blocks co-resident (capacity margins documented above).
// ---------------------------------------------------------------------------
__device__ __forceinline__ void gridbar(int* bar, int nb) {
    __threadfence();                      // release my writes (agent scope)
    __syncthreads();
    if (threadIdx.x == 0) {
        int g = __hip_atomic_load(&bar[1], __ATOMIC_ACQUIRE,
                                  __HIP_MEMORY_SCOPE_AGENT);
        if (atomicAdd(&bar[0], 1) == nb - 1) {
            __hip_atomic_store(&bar[0], 0, __ATOMIC_RELAXED,
                               __HIP_MEMORY_SCOPE_AGENT);
            __hip_atomic_store(&bar[1], g + 1, __ATOMIC_RELEASE,
                               __HIP_MEMORY_SCOPE_AGENT);
        } else {
            while (__hip_atomic_load(&bar[1], __ATOMIC_ACQUIRE,
                                     __HIP_MEMORY_SCOPE_AGENT) == g)
                __builtin_amdgcn_s_sleep(2);
        }
    }
    __syncthreads();
    __threadfence();                      // acquire side
}

// ---------------------------------------------------------------------------
// Persistent pre-chain: cast/hist/invp -> alloc -> scatter -> agg.
// Phase bodies verbatim from the proven R9 kernels, grid-strided.
// ---------------------------------------------------------------------------
__global__ __launch_bounds__(256, 4) void k_pre(
    const int* __restrict__ eidx, const int* __restrict__ etype,
    const int* __restrict__ etime, const float* __restrict__ ew,
    const int* __restrict__ perm, const float* __restrict__ ent,
    const float* __restrict__ rel, const float* __restrict__ tim,
    const float* __restrict__ Wi, const float* __restrict__ Wo,
    ushort_t* __restrict__ entb, ushort_t* __restrict__ relb,
    ushort_t* __restrict__ timb, ushort_t* __restrict__ WiT,
    ushort_t* __restrict__ WoT, int* __restrict__ hist,
    int* __restrict__ gcnt, int* __restrict__ bar,
    int* __restrict__ cursor, int* __restrict__ rowst,
    int* __restrict__ invp, int2* __restrict__ esort,
    ushort_t* __restrict__ xbf)
{
    int tid  = threadIdx.x;
    int gidx = blockIdx.x * 256 + tid;
    int lane = tid & 63;
    int gw   = blockIdx.x * 4 + (tid >> 6);      // global wave id [0, PREW)
    const int* dstp = eidx + E;

    // ---- phase A: cast tables/weights + hist + invp (grid-stride) ----
    for (size_t t = gidx; t < CAST_TOT; t += PRET) {
        if (t < CAST_TBL) {
            const float2* s; uint_t* d; size_t off;
            if (t < 3200000)      { s = (const float2*)ent; d = (uint_t*)entb; off = t; }
            else if (t < 3212800) { s = (const float2*)rel; d = (uint_t*)relb; off = t - 3200000; }
            else                  { s = (const float2*)tim; d = (uint_t*)timb; off = t - 3212800; }
            float2 v = s[off];
            d[off] = (uint_t)f2us(v.x) | ((uint_t)f2us(v.y) << 16);
        } else if (t < CAST_W) {
            size_t u = t - CAST_TBL;
            if (u < (size_t)L * 256 * 128) {
                int l = u / (256 * 128), r = u % (256 * 128);
                int n = r / 128, k = r % 128;
                WiT[u] = f2us(Wi[(size_t)l * 128 * 256 + k * 256 + n]);
            } else {
                size_t v = u - (size_t)L * 256 * 128;
                int l = v / (128 * 128), r = v % (128 * 128);
                int n = r / 128, k = r % 128;
                WoT[v] = f2us(Wo[(size_t)l * 128 * 128 + k * 128 + n]);
            }
        } else if (t < CAST_H) {
            int e = (int)(t - CAST_W);
            atomicAdd(&hist[dstp[e]], 1);
        } else {
            int i = (int)(t - CAST_H);
            invp[perm[i]] = i;
        }
    }
    gridbar(bar, PREB);

    // ---- phase B: slot alloc (one wave per 64-row chunk) ----
    for (int c = gw; c * 64 < N; c += PREW) {
        int i = c * 64 + lane;
        int v = (i < N) ? hist[i] : 0;
        int s = v;
        #pragma unroll
        for (int m = 1; m < 64; m <<= 1) {
            int t = __shfl_up(s, m, 64);
            if (lane >= m) s += t;
        }
        int base = 0;
        if (lane == 63) base = atomicAdd(gcnt, s);
        base = __shfl(base, 63, 64);
        int b = base + s - v;
        if (i < N) {
            cursor[i] = b;
            rowst[i]  = b;
        }
    }
    gridbar(bar, PREB);

    // ---- phase C: scatter packed records ----
    for (int e = gidx; e < E; e += PRET) {
        int dst = dstp[e];
        int slot = atomicAdd(&cursor[dst], 1);
        int2 p;
        p.x = (eidx[e] & 0xffff) | (etype[e] << 16);
        p.y = (etime[e] & 0xffff) | ((int)f2us(ew[e]) << 16);
        esort[slot] = p;
    }
    gridbar(bar, PREB);

    // ---- phase D: aggregation, one wave per dst ----
    {
        const uint_t* entu = (const uint_t*)entb;   // 64 dwords per row
        const uint_t* relu = (const uint_t*)relb;
        const uint_t* timu = (const uint_t*)timb;
        for (int d = gw; d < N; d += PREW) {
            int beg = __builtin_amdgcn_readfirstlane(rowst[d]);
            int n   = __builtin_amdgcn_readfirstlane(hist[d]);

            float s0[4] = {0.f, 0.f, 0.f, 0.f};
            float s1[4] = {0.f, 0.f, 0.f, 0.f};
            float wacc = 0.f;

            for (int c0 = 0; c0 < n; c0 += 64) {
                int mm = n - c0; if (mm > 64) mm = 64;
                int2 rec = esort[beg + c0 + lane];
                uint_t recx = (uint_t)rec.x, recy = (uint_t)rec.y;
                wacc += (lane < mm) ? u2f(recy & 0xffff0000u) : 0.f;

                int j = 0;
                for (; j + 3 < mm; j += 4) {
                    #pragma unroll
                    for (int u = 0; u < 4; u++) {
                        uint_t rx = (uint_t)__builtin_amdgcn_readlane((int)recx, j + u);
                        uint_t ry = (uint_t)__builtin_amdgcn_readlane((int)recy, j + u);
                        const uint_t* pe = entu + ((size_t)(rx & 0xffffu) << 6);
                        const uint_t* pr = relu + ((size_t)(rx >> 16) << 6);
                        const uint_t* pt = timu + ((size_t)(ry & 0xffffu) << 6);
                        float w = u2f(ry & 0xffff0000u);
                        uint_t va = pe[lane];
                        uint_t vb = pr[lane];
                        uint_t vc = pt[lane];
                        float lo = (u2f(va << 16) + u2f(vb << 16)) + u2f(vc << 16);
                        float hi = (u2f(va & 0xffff0000u) + u2f(vb & 0xffff0000u))
                                 + u2f(vc & 0xffff0000u);
                        s0[u] = fmaf(lo, w, s0[u]);
                        s1[u] = fmaf(hi, w, s1[u]);
                    }
                }
                for (; j < mm; j++) {
                    uint_t rx = (uint_t)__builtin_amdgcn_readlane((int)recx, j);
                    uint_t ry = (uint_t)__builtin_amdgcn_readlane((int)recy, j);
                    const uint_t* pe = entu + ((size_t)(rx & 0xffffu) << 6);
                    const uint_t* pr = relu + ((size_t)(rx >> 16) << 6);
                    const uint_t* pt = timu + ((size_t)(ry & 0xffffu) << 6);
                    float w = u2f(ry & 0xffff0000u);
                    uint_t va = pe[lane];
                    uint_t vb = pr[lane];
                    uint_t vc = pt[lane];
                    float lo = (u2f(va << 16) + u2f(vb << 16)) + u2f(vc << 16);
                    float hi = (u2f(va & 0xffff0000u) + u2f(vb & 0xffff0000u))
                             + u2f(vc & 0xffff0000u);
                    s0[0] = fmaf(lo, w, s0[0]);
                    s1[0] = fmaf(hi, w, s1[0]);
                }
            }
            float a0 = (s0[0] + s0[1]) + (s0[2] + s0[3]);
            float a1 = (s1[0] + s1[1]) + (s1[2] + s1[3]);

            float wsum = wacc;
            #pragma unroll
            for (int m = 32; m >= 1; m >>= 1) wsum += __shfl_xor(wsum, m, 64);

            float inv = 1.0f / fmaxf(wsum, 1.0f);
            a0 *= inv; a1 *= inv;

            float ss = a0 * a0 + a1 * a1;
            #pragma unroll
            for (int m = 32; m >= 1; m >>= 1) ss += __shfl_xor(ss, m, 64);
            float sc = 1.0f / fmaxf(sqrtf(ss), 1e-12f);

            int orow = invp[d];
            uint_t out = (uint_t)f2us(a0 * sc) | ((uint_t)f2us(a1 * sc) << 16);
            *(uint_t*)(xbf + (size_t)orow * D + 2 * lane) = out;
        }
    }
}

// ---------------------------------------------------------------------------
// Fused mamba layer body (R8/R9-proven; r0 parameterized for grid-stride).
// ---------------------------------------------------------------------------
template <bool FINAL>
__device__ __forceinline__ void layer_body(
    int r0, ushort_t* SCA, ushort_t* SCB, float* redS, float* redQ,
    float* muA, float* rsA,
    const ushort_t* __restrict__ xin, const ushort_t* __restrict__ WiT,
    const float* __restrict__ bi, const ushort_t* __restrict__ WoT,
    const float* __restrict__ bo, const float* __restrict__ Aw,
    const float* __restrict__ Bw, const float* __restrict__ lg,
    const float* __restrict__ lb, ushort_t* __restrict__ xoutb,
    float* __restrict__ outf)
{
    int tid = threadIdx.x;
    int w = tid >> 6, lane = tid & 63;
    int quad = lane >> 4, m = lane & 15;

    int cz0 = w * 32 + m, cz1 = cz0 + 16;

    float Ad0 = Aw[cz0], Bd0 = Bw[cz0];
    float Ad1 = Aw[cz1], Bd1 = Bw[cz1];
    float bz0 = bi[cz0], bz1 = bi[cz1];
    float bg0 = bi[cz0 + 128], bg1 = bi[cz1 + 128];

    const f32x4 zero4 = {0.f, 0.f, 0.f, 0.f};

    bf8 Bz0[4], Bz1[4], Bg0[4], Bg1[4];
    #pragma unroll
    for (int kb = 0; kb < 4; kb++) {
        int ko = kb * 32 + quad * 8;
        Bz0[kb] = *(const bf8*)(WiT + (size_t)cz0 * 128 + ko);
        Bz1[kb] = *(const bf8*)(WiT + (size_t)cz1 * 128 + ko);
        Bg0[kb] = *(const bf8*)(WiT + (size_t)(cz0 + 128) * 128 + ko);
        Bg1[kb] = *(const bf8*)(WiT + (size_t)(cz1 + 128) * 128 + ko);
    }

    // ---- phase 1: zg for rows r0-16 .. r0+79 (6 tiles), coeff -> LDS ----
    #pragma unroll
    for (int rt = 0; rt < CROWS / 16; rt++) {
        int gr = r0 - LOOK + rt * 16 + m;
        int grc = gr < 0 ? 0 : gr;
        bf8 a[4];
        #pragma unroll
        for (int kb = 0; kb < 4; kb++)
            a[kb] = *(const bf8*)(xin + (size_t)grc * 128 + kb * 32 + quad * 8);
        f32x4 az0 = zero4, az1 = zero4, ag0 = zero4, ag1 = zero4;
        #pragma unroll
        for (int kb = 0; kb < 4; kb++) {
            az0 = __builtin_amdgcn_mfma_f32_16x16x32_bf16(a[kb], Bz0[kb], az0, 0, 0, 0);
            az1 = __builtin_amdgcn_mfma_f32_16x16x32_bf16(a[kb], Bz1[kb], az1, 0, 0, 0);
            ag0 = __builtin_amdgcn_mfma_f32_16x16x32_bf16(a[kb], Bg0[kb], ag0, 0, 0, 0);
            ag1 = __builtin_amdgcn_mfma_f32_16x16x32_bf16(a[kb], Bg1[kb], ag1, 0, 0, 0);
        }
        #pragma unroll
        for (int reg = 0; reg < 4; reg++) {
            int lr = rt * 16 + quad * 4 + reg;
            float z0 = az0[reg] + bz0, z1 = az1[reg] + bz1;
            float g0 = 1.f / (1.f + __expf(-(ag0[reg] + bg0)));
            float g1 = 1.f / (1.f + __expf(-(ag1[reg] + bg1)));
            SCA[lr * CSTR + cz0] = f2us(g0 * Ad0);
            SCB[lr * CSTR + cz0] = f2us(Bd0 * z0);
            SCA[lr * CSTR + cz1] = f2us(g1 * Ad1);
            SCB[lr * CSTR + cz1] = f2us(Bd1 * z1);
        }
    }
    __syncthreads();

    // ---- phase 2a: group2 prefetches its lookback (rows 40..55) to regs ----
    int dmm = tid & 127;
    float lca[LOOK], lcb[LOOK];
    if (tid >= 128) {
        #pragma unroll
        for (int i = 0; i < LOOK; i++) {
            lca[i] = us2f(SCA[(40 + i) * CSTR + dmm]);
            lcb[i] = us2f(SCB[(40 + i) * CSTR + dmm]);
        }
    }
    __syncthreads();

    // ---- phase 2b: split scan (56-step chains); h -> SCA in place ----
    if (tid < 128) {
        float h = 0.f;
        #pragma unroll
        for (int i = 0; i < LOOK; i++) {
            int row = r0 - LOOK + i;
            float ca = us2f(SCA[i * CSTR + tid]);
            float cb = us2f(SCB[i * CSTR + tid]);
            h = (row >= 0) ? fmaf(ca, h, cb) : 0.f;
        }
        #pragma unroll 8
        for (int i = LOOK; i < LOOK + 40; i++) {
            float ca = us2f(SCA[i * CSTR + tid]);
            float cb = us2f(SCB[i * CSTR + tid]);
            h = fmaf(ca, h, cb);
            SCA[i * CSTR + tid] = f2us(h);
        }
    } else {
        float h = 0.f;
        #pragma unroll
        for (int i = 0; i < LOOK; i++)
            h = fmaf(lca[i], h, lcb[i]);
        #pragma unroll 8
        for (int i = 56; i < 96; i++) {
            float ca = us2f(SCA[i * CSTR + dmm]);
            float cb = us2f(SCB[i * CSTR + dmm]);
            h = fmaf(ca, h, cb);
            SCA[i * CSTR + dmm] = f2us(h);
        }
    }
    __syncthreads();

    // ---- phase 3: per 16-row tile: y = x + h@Wo + bo, LN, store ----
    bf8 b0[4], b1[4];
    #pragma unroll
    for (int kb = 0; kb < 4; kb++) {
        int ko = kb * 32 + quad * 8;
        b0[kb] = *(const bf8*)(WoT + (size_t)cz0 * 128 + ko);
        b1[kb] = *(const bf8*)(WoT + (size_t)cz1 * 128 + ko);
    }
    float bias0 = bo[cz0], bias1 = bo[cz1];
    float gl0 = lg[cz0], gl1 = lg[cz1], bl0 = lb[cz0], bl1 = lb[cz1];

    for (int rt = 0; rt < RB / 16; rt++) {
        bf8 a[4];
        #pragma unroll
        for (int kb = 0; kb < 4; kb++)
            a[kb] = *(const bf8*)(SCA + (LOOK + rt * 16 + m) * CSTR
                                      + kb * 32 + quad * 8);
        f32x4 acc0 = {0.f, 0.f, 0.f, 0.f}, acc1 = acc0;
        #pragma unroll
        for (int kb = 0; kb < 4; kb++) {
            acc0 = __builtin_amdgcn_mfma_f32_16x16x32_bf16(a[kb], b0[kb], acc0, 0, 0, 0);
            acc1 = __builtin_amdgcn_mfma_f32_16x16x32_bf16(a[kb], b1[kb], acc1, 0, 0, 0);
        }
        float y0[4], y1[4];
        #pragma unroll
        for (int reg = 0; reg < 4; reg++) {
            int gr = r0 + rt * 16 + quad * 4 + reg;
            y0[reg] = acc0[reg] + bias0 + us2f(xin[(size_t)gr * 128 + cz0]);
            y1[reg] = acc1[reg] + bias1 + us2f(xin[(size_t)gr * 128 + cz1]);
        }
        #pragma unroll
        for (int reg = 0; reg < 4; reg++) {
            float v0 = y0[reg], v1 = y1[reg];
            float s = v0 + v1, q = v0 * v0 + v1 * v1;
            #pragma unroll
            for (int mk = 1; mk <= 8; mk <<= 1) {
                s += __shfl_xor(s, mk, 64);
                q += __shfl_xor(q, mk, 64);
            }
            if (m == 0) {
                int row = quad * 4 + reg;
                redS[row * 4 + w] = s;
                redQ[row * 4 + w] = q;
            }
        }
        __syncthreads();
        if (tid < 16) {
            float s = redS[tid * 4] + redS[tid * 4 + 1] + redS[tid * 4 + 2] + redS[tid * 4 + 3];
            float q = redQ[tid * 4] + redQ[tid * 4 + 1] + redQ[tid * 4 + 2] + redQ[tid * 4 + 3];
            float mu = s * (1.f / 128.f);
            float var = q * (1.f / 128.f) - mu * mu;
            muA[tid] = mu;
            rsA[tid] = rsqrtf(var + 1e-5f);
        }
        __syncthreads();
        #pragma unroll
        for (int reg = 0; reg < 4; reg++) {
            int rr = quad * 4 + reg;
            int gr = r0 + rt * 16 + rr;
            float mu = muA[rr], rs = rsA[rr];
            float v0 = (y0[reg] - mu) * rs * gl0 + bl0;
            float v1 = (y1[reg] - mu) * rs * gl1 + bl1;
            if (FINAL) {
                outf[(size_t)gr * 128 + cz0] = v0;
                outf[(size_t)gr * 128 + cz1] = v1;
            } else {
                xoutb[(size_t)gr * 128 + cz0] = f2us(v0);
                xoutb[(size_t)gr * 128 + cz1] = f2us(v1);
            }
        }
    }
}

// ---------------------------------------------------------------------------
// Persistent double-layer kernel: layer0 tiles -> software grid barrier ->
// layer1 tiles.  416 blocks, 2 blocks/CU guaranteed by LDS arithmetic.
// ---------------------------------------------------------------------------
__global__ __launch_bounds__(256, 2) void k_layers(
    const ushort_t* __restrict__ xbf, ushort_t* __restrict__ xb2,
    const ushort_t* __restrict__ WiT, const float* __restrict__ bi,
    const ushort_t* __restrict__ WoT, const float* __restrict__ bo,
    const float* __restrict__ Aw, const float* __restrict__ Bw,
    const float* __restrict__ lg, const float* __restrict__ lb,
    int* __restrict__ bar, float* __restrict__ outf)
{
    __shared__ ushort_t SCA[CROWS * CSTR];
    __shared__ ushort_t SCB[CROWS * CSTR];
    __shared__ float redS[16 * 4], redQ[16 * 4], muA[16], rsA[16];

    for (int t = blockIdx.x; t < RBLK; t += LBLK) {
        __syncthreads();        // LDS reuse fence between tiles
        layer_body<false>(t * RB, SCA, SCB, redS, redQ, muA, rsA,
                          xbf, WiT, bi, WoT, bo, Aw, Bw, lg, lb,
                          xb2, nullptr);
    }
    gridbar(bar, LBLK);
    for (int t = blockIdx.x; t < RBLK; t += LBLK) {
        __syncthreads();
        layer_body<true>(t * RB, SCA, SCB, redS, redQ, muA, rsA,
                         xb2, WiT + (size_t)256 * 128, bi + 256,
                         WoT + (size_t)128 * 128, bo + 128,
                         Aw + 128, Bw + 128, lg + 128, lb + 128,
                         nullptr, outf);
    }
}

extern "C" void kernel_launch(void* const* d_in, const int* in_sizes, int n_in,
                              void* d_out, int out_size, void* d_ws, size_t ws_size,
                              hipStream_t stream)
{
    const int*   eidx  = (const int*)d_in[0];
    const int*   etype = (const int*)d_in[1];
    const int*   etime = (const int*)d_in[2];
    const float* ew    = (const float*)d_in[3];
    const int*   perm  = (const int*)d_in[4];
    const float* ent   = (const float*)d_in[5];
    const float* rel   = (const float*)d_in[6];
    const float* tim   = (const float*)d_in[7];
    const float* Wi    = (const float*)d_in[8];
    const float* bi    = (const float*)d_in[9];
    const float* Wo    = (const float*)d_in[10];
    const float* bo    = (const float*)d_in[11];
    const float* Aw    = (const float*)d_in[12];
    const float* Bw    = (const float*)d_in[13];
    const float* lg    = (const float*)d_in[14];
    const float* lbp   = (const float*)d_in[15];

    char* base = (char*)d_ws;
    size_t o = 0;
    ushort_t* xbf  = (ushort_t*)(base + o); o += (size_t)N * D * 2;
    ushort_t* xb2  = (ushort_t*)(base + o); o += (size_t)N * D * 2;
    ushort_t* entb = (ushort_t*)(base + o); o += (size_t)N * D * 2;
    ushort_t* relb = (ushort_t*)(base + o); o += (size_t)200 * D * 2;
    ushort_t* timb = (ushort_t*)(base + o); o += (size_t)1000 * D * 2;
    ushort_t* WiT  = (ushort_t*)(base + o); o += (size_t)L * 256 * 128 * 2;
    ushort_t* WoT  = (ushort_t*)(base + o); o += (size_t)L * 128 * 128 * 2;
    int2*     esort  = (int2*)(base + o);   o += (size_t)E * 8;
    int*      hist   = (int*)(base + o);    o += (size_t)N * 4;
    int*      gcnt   = (int*)(base + o);    o += 4;      // hist[N]
    int*      barA   = (int*)(base + o);    o += 8;      // pre-chain barrier
    int*      barB   = (int*)(base + o);    o += 8;      // layer barrier
    int*      cursor = (int*)(base + o);    o += (size_t)N * 4;
    int*      rowst  = (int*)(base + o);    o += (size_t)N * 4;
    int*      invp   = (int*)(base + o);    o += (size_t)N * 4;

    // zero hist + gcnt + barA + barB in one contiguous memset
    hipMemsetAsync(hist, 0, (N + 5) * sizeof(int), stream);

    k_pre<<<PREB, 256, 0, stream>>>(
        eidx, etype, etime, ew, perm, ent, rel, tim, Wi, Wo,
        entb, relb, timb, WiT, WoT, hist, gcnt, barA,
        cursor, rowst, invp, esort, xbf);

    k_layers<<<LBLK, 256, 0, stream>>>(
        xbf, xb2, WiT, bi, WoT, bo, Aw, Bw, lg, lbp, barB, (float*)d_out);
}

// Round 12
// 284.102 us; speedup vs baseline: 2.9747x; 2.9747x over previous
//
#include <hip/hip_runtime.h>
#include <hip/hip_bf16.h>

typedef unsigned short ushort_t;
typedef unsigned int   uint_t;
typedef __attribute__((ext_vector_type(8))) short bf8;
typedef __attribute__((ext_vector_type(4))) float f32x4;

constexpr int N = 50000;
constexpr int E = 600000;
constexpr int D = 128;
constexpr int L = 2;
constexpr int NB = (N + 255) / 256;

// fused layer tiling: 80 output rows/block (N/80 = 625 exact) + 16 lookback
// rows recomputed per block (decay |g*A|^16 ~ 2e-8).  coeff lives in LDS:
// two bf16 planes SCA/SCB[96][CSTR]; h overwrites SCA rows 16..95 in place.
// CSTR=136 u16 (272B) -> 16B-aligned b128 reads.  (R5/R6 lesson: a packed
// u32 plane needs stride >= 128 u32/row; PSTR=68 overran into the next row.)
// LDS 52864 B; launch_bounds(256,3): 3 x 52.9KB = 158.6KB <= 160KB/CU.
// (R9/R10 lesson: cooperative launch unsupported by harness capture;
// persistent-block fusion caps agg at ~2k waves vs the ~50k it needs ->
// 3x regression.  Wide per-phase grids + normal dispatches are the floor.)
constexpr int RB   = 80;
constexpr int RBLK = N / RB;   // 625
constexpr int LOOK = 16;
constexpr int CSTR = 136;
constexpr int CROWS = RB + LOOK;   // 96

__device__ __forceinline__ float us2f(ushort_t u) {
    union { uint_t i; float f; } c; c.i = (uint_t)u << 16; return c.f;
}
__device__ __forceinline__ float u2f(uint_t u) {
    union { uint_t i; float f; } c; c.i = u; return c.f;
}
__device__ __forceinline__ ushort_t f2us(float f) {
    __hip_bfloat16 b = __float2bfloat16(f);
    return *(ushort_t*)&b;
}

// ---------------------------------------------------------------------------
// Slot allocation: per-dst contiguous ranges via wave-prefix + one global
// atomic per wave (global dst order nondeterministic; per-dst record order
// and fp sum order unchanged).
// ---------------------------------------------------------------------------
__global__ __launch_bounds__(256) void k_alloc(
    const int* __restrict__ hist, int* __restrict__ gcnt,
    int* __restrict__ cursor, int* __restrict__ rowst)
{
    int i = blockIdx.x * 256 + threadIdx.x;
    int v = (i < N) ? hist[i] : 0;
    int lane = threadIdx.x & 63;
    int s = v;
    #pragma unroll
    for (int m = 1; m < 64; m <<= 1) {
        int t = __shfl_up(s, m, 64);
        if (lane >= m) s += t;
    }
    int base = 0;
    if (lane == 63) base = atomicAdd(gcnt, s);
    base = __shfl(base, 63, 64);
    int b = base + s - v;
    if (i < N) {
        cursor[i] = b;
        rowst[i]  = b;
    }
}

// packed record: x = src | (type<<16); y = time | (w_bf16<<16)
__global__ __launch_bounds__(256) void k_scatter(
    const int* __restrict__ eidx, const int* __restrict__ etype,
    const int* __restrict__ etime, const float* __restrict__ ew,
    int* __restrict__ cursor, int2* __restrict__ esort)
{
    int e = blockIdx.x * 256 + threadIdx.x;
    if (e >= E) return;
    int dst = eidx[E + e];
    int slot = atomicAdd(&cursor[dst], 1);
    int2 p;
    p.x = (eidx[e] & 0xffff) | (etype[e] << 16);
    p.y = (etime[e] & 0xffff) | ((int)f2us(ew[e]) << 16);
    esort[slot] = p;
}

// ---------------------------------------------------------------------------
// Fused cast + hist + invp
// ---------------------------------------------------------------------------
constexpr size_t CAST_TBL = 3276800;                               // table f2 elems
constexpr size_t CAST_W   = CAST_TBL + (size_t)L * 256 * 128
                                     + (size_t)L * 128 * 128;      // 3,375,104
constexpr size_t CAST_H   = CAST_W + E;                            // + hist
constexpr size_t CAST_TOT = CAST_H + N;                            // + invp

__global__ __launch_bounds__(256) void k_cast(
    const float* __restrict__ ent, const float* __restrict__ rel,
    const float* __restrict__ tim, const float* __restrict__ Wi,
    const float* __restrict__ Wo, const int* __restrict__ dstp,
    const int* __restrict__ perm,
    ushort_t* __restrict__ entb, ushort_t* __restrict__ relb,
    ushort_t* __restrict__ timb, ushort_t* __restrict__ WiT,
    ushort_t* __restrict__ WoT, int* __restrict__ hist,
    int* __restrict__ invp)
{
    size_t t = (size_t)blockIdx.x * 256 + threadIdx.x;
    if (t < CAST_TBL) {
        const float2* s; uint_t* d; size_t off;
        if (t < 3200000)      { s = (const float2*)ent; d = (uint_t*)entb; off = t; }
        else if (t < 3212800) { s = (const float2*)rel; d = (uint_t*)relb; off = t - 3200000; }
        else                  { s = (const float2*)tim; d = (uint_t*)timb; off = t - 3212800; }
        float2 v = s[off];
        d[off] = (uint_t)f2us(v.x) | ((uint_t)f2us(v.y) << 16);
    } else if (t < CAST_W) {
        size_t u = t - CAST_TBL;
        if (u < (size_t)L * 256 * 128) {
            int l = u / (256 * 128), r = u % (256 * 128);
            int n = r / 128, k = r % 128;
            WiT[u] = f2us(Wi[(size_t)l * 128 * 256 + k * 256 + n]);
        } else {
            size_t v = u - (size_t)L * 256 * 128;
            int l = v / (128 * 128), r = v % (128 * 128);
            int n = r / 128, k = r % 128;
            WoT[v] = f2us(Wo[(size_t)l * 128 * 128 + k * 128 + n]);
        }
    } else if (t < CAST_H) {
        int e = (int)(t - CAST_W);
        atomicAdd(&hist[dstp[e]], 1);
    } else if (t < CAST_TOT) {
        int i = (int)(t - CAST_H);
        invp[perm[i]] = i;
    }
}

// ---------------------------------------------------------------------------
// Aggregation: one wave per dst row (records staged cooperatively, broadcast
// via v_readlane; gathers in saddr form).  Near random-gather floor.
// Needs the full-width grid (~50k waves) to cover HBM gather latency.
// ---------------------------------------------------------------------------
__global__ __launch_bounds__(256) void k_agg(
    const int2* __restrict__ esort, const int* __restrict__ rowst,
    const int* __restrict__ hist, const int* __restrict__ invp,
    const ushort_t* __restrict__ entb, const ushort_t* __restrict__ relb,
    const ushort_t* __restrict__ timb, ushort_t* __restrict__ xbf)
{
    int wv = threadIdx.x >> 6, lane = threadIdx.x & 63;
    int d = blockIdx.x * 4 + wv;
    if (d >= N) return;
    int beg = __builtin_amdgcn_readfirstlane(rowst[d]);
    int n   = __builtin_amdgcn_readfirstlane(hist[d]);

    const uint_t* entu = (const uint_t*)entb;   // 64 dwords per row
    const uint_t* relu = (const uint_t*)relb;
    const uint_t* timu = (const uint_t*)timb;

    float s0[4] = {0.f, 0.f, 0.f, 0.f};
    float s1[4] = {0.f, 0.f, 0.f, 0.f};
    float wacc = 0.f;

    for (int c0 = 0; c0 < n; c0 += 64) {
        int mm = n - c0; if (mm > 64) mm = 64;
        int2 rec = esort[beg + c0 + lane];
        uint_t recx = (uint_t)rec.x, recy = (uint_t)rec.y;
        wacc += (lane < mm) ? u2f(recy & 0xffff0000u) : 0.f;

        int j = 0;
        for (; j + 3 < mm; j += 4) {
            #pragma unroll
            for (int u = 0; u < 4; u++) {
                uint_t rx = (uint_t)__builtin_amdgcn_readlane((int)recx, j + u);
                uint_t ry = (uint_t)__builtin_amdgcn_readlane((int)recy, j + u);
                const uint_t* pe = entu + ((size_t)(rx & 0xffffu) << 6);
                const uint_t* pr = relu + ((size_t)(rx >> 16) << 6);
                const uint_t* pt = timu + ((size_t)(ry & 0xffffu) << 6);
                float w = u2f(ry & 0xffff0000u);
                uint_t va = pe[lane];
                uint_t vb = pr[lane];
                uint_t vc = pt[lane];
                float lo = (u2f(va << 16) + u2f(vb << 16)) + u2f(vc << 16);
                float hi = (u2f(va & 0xffff0000u) + u2f(vb & 0xffff0000u))
                         + u2f(vc & 0xffff0000u);
                s0[u] = fmaf(lo, w, s0[u]);
                s1[u] = fmaf(hi, w, s1[u]);
            }
        }
        for (; j < mm; j++) {
            uint_t rx = (uint_t)__builtin_amdgcn_readlane((int)recx, j);
            uint_t ry = (uint_t)__builtin_amdgcn_readlane((int)recy, j);
            const uint_t* pe = entu + ((size_t)(rx & 0xffffu) << 6);
            const uint_t* pr = relu + ((size_t)(rx >> 16) << 6);
            const uint_t* pt = timu + ((size_t)(ry & 0xffffu) << 6);
            float w = u2f(ry & 0xffff0000u);
            uint_t va = pe[lane];
            uint_t vb = pr[lane];
            uint_t vc = pt[lane];
            float lo = (u2f(va << 16) + u2f(vb << 16)) + u2f(vc << 16);
            float hi = (u2f(va & 0xffff0000u) + u2f(vb & 0xffff0000u))
                     + u2f(vc & 0xffff0000u);
            s0[0] = fmaf(lo, w, s0[0]);
            s1[0] = fmaf(hi, w, s1[0]);
        }
    }
    float a0 = (s0[0] + s0[1]) + (s0[2] + s0[3]);
    float a1 = (s1[0] + s1[1]) + (s1[2] + s1[3]);

    float wsum = wacc;
    #pragma unroll
    for (int m = 32; m >= 1; m >>= 1) wsum += __shfl_xor(wsum, m, 64);

    float inv = 1.0f / fmaxf(wsum, 1.0f);
    a0 *= inv; a1 *= inv;

    float ss = a0 * a0 + a1 * a1;
    #pragma unroll
    for (int m = 32; m >= 1; m >>= 1) ss += __shfl_xor(ss, m, 64);
    float sc = 1.0f / fmaxf(sqrtf(ss), 1e-12f);

    int orow = invp[d];
    uint_t out = (uint_t)f2us(a0 * sc) | ((uint_t)f2us(a1 * sc) << 16);
    *(uint_t*)(xbf + (size_t)orow * D + 2 * lane) = out;
}

// ---------------------------------------------------------------------------
// Fully-fused mamba layer (proven @282.9us):
//   phase 1: zg MFMA (6 tiles incl. lookback) -> ca,cb bf16 -> SCA/SCB (LDS)
//   phase 2: SPLIT scan, all 256 threads (56-step chains):
//     group1 (tid<128): lookback rows 0..15, output rows 16..55 (h in place)
//     group2 (tid>=128): lookback rows 40..55 PREFETCHED TO REGS before the
//       barrier (group1's in-place h stores overwrite rows 40..55 later),
//       output rows 56..95.  Rows 40..79 use a truncated 16-row lookback —
//       the same approximation every block boundary already uses
//       (|g*A|^16 ~ 2e-8 carry-through).
//   phase 3: per 16-row tile: y = x + h@Wo + bo -> LN (2-barrier) -> store
// ---------------------------------------------------------------------------
template <bool FINAL>
__global__ __launch_bounds__(256, 3) void k_layer(
    const ushort_t* __restrict__ xin, const ushort_t* __restrict__ WiT,
    const float* __restrict__ bi, const ushort_t* __restrict__ WoT,
    const float* __restrict__ bo, const float* __restrict__ Aw,
    const float* __restrict__ Bw, const float* __restrict__ lg,
    const float* __restrict__ lb, ushort_t* __restrict__ xoutb,
    float* __restrict__ outf)
{
    __shared__ ushort_t SCA[CROWS * CSTR];   // ca; h overwrites rows 16..95
    __shared__ ushort_t SCB[CROWS * CSTR];   // cb
    __shared__ float redS[16 * 4], redQ[16 * 4], muA[16], rsA[16];

    int tid = threadIdx.x;
    int w = tid >> 6, lane = tid & 63;
    int quad = lane >> 4, m = lane & 15;
    int r0 = blockIdx.x * RB;

    int cz0 = w * 32 + m, cz1 = cz0 + 16;

    float Ad0 = Aw[cz0], Bd0 = Bw[cz0];
    float Ad1 = Aw[cz1], Bd1 = Bw[cz1];
    float bz0 = bi[cz0], bz1 = bi[cz1];
    float bg0 = bi[cz0 + 128], bg1 = bi[cz1 + 128];

    const f32x4 zero4 = {0.f, 0.f, 0.f, 0.f};

    // Wi B-fragments: 4 col-subtiles (z0,z1,g0,g1) x 4 kb — loaded once
    bf8 Bz0[4], Bz1[4], Bg0[4], Bg1[4];
    #pragma unroll
    for (int kb = 0; kb < 4; kb++) {
        int ko = kb * 32 + quad * 8;
        Bz0[kb] = *(const bf8*)(WiT + (size_t)cz0 * 128 + ko);
        Bz1[kb] = *(const bf8*)(WiT + (size_t)cz1 * 128 + ko);
        Bg0[kb] = *(const bf8*)(WiT + (size_t)(cz0 + 128) * 128 + ko);
        Bg1[kb] = *(const bf8*)(WiT + (size_t)(cz1 + 128) * 128 + ko);
    }

    // ---- phase 1: zg for rows r0-16 .. r0+79 (6 tiles), coeff -> LDS ----
    #pragma unroll
    for (int rt = 0; rt < CROWS / 16; rt++) {
        int gr = r0 - LOOK + rt * 16 + m;
        int grc = gr < 0 ? 0 : gr;             // clamp (block 0 only; h=0 later)
        bf8 a[4];
        #pragma unroll
        for (int kb = 0; kb < 4; kb++)
            a[kb] = *(const bf8*)(xin + (size_t)grc * 128 + kb * 32 + quad * 8);
        f32x4 az0 = zero4, az1 = zero4, ag0 = zero4, ag1 = zero4;
        #pragma unroll
        for (int kb = 0; kb < 4; kb++) {
            az0 = __builtin_amdgcn_mfma_f32_16x16x32_bf16(a[kb], Bz0[kb], az0, 0, 0, 0);
            az1 = __builtin_amdgcn_mfma_f32_16x16x32_bf16(a[kb], Bz1[kb], az1, 0, 0, 0);
            ag0 = __builtin_amdgcn_mfma_f32_16x16x32_bf16(a[kb], Bg0[kb], ag0, 0, 0, 0);
            ag1 = __builtin_amdgcn_mfma_f32_16x16x32_bf16(a[kb], Bg1[kb], ag1, 0, 0, 0);
        }
        // C/D layout: row = quad*4 + reg, col = cz0/cz1
        #pragma unroll
        for (int reg = 0; reg < 4; reg++) {
            int lr = rt * 16 + quad * 4 + reg;          // LDS row 0..95
            float z0 = az0[reg] + bz0, z1 = az1[reg] + bz1;
            float g0 = 1.f / (1.f + __expf(-(ag0[reg] + bg0)));
            float g1 = 1.f / (1.f + __expf(-(ag1[reg] + bg1)));
            SCA[lr * CSTR + cz0] = f2us(g0 * Ad0);
            SCB[lr * CSTR + cz0] = f2us(Bd0 * z0);
            SCA[lr * CSTR + cz1] = f2us(g1 * Ad1);
            SCB[lr * CSTR + cz1] = f2us(Bd1 * z1);
        }
    }
    __syncthreads();

    // ---- phase 2a: group2 prefetches its lookback (rows 40..55) to regs ----
    int dmm = tid & 127;
    float lca[LOOK], lcb[LOOK];
    if (tid >= 128) {
        #pragma unroll
        for (int i = 0; i < LOOK; i++) {
            lca[i] = us2f(SCA[(40 + i) * CSTR + dmm]);
            lcb[i] = us2f(SCB[(40 + i) * CSTR + dmm]);
        }
    }
    __syncthreads();

    // ---- phase 2b: both groups scan 56-step chains; h -> SCA in place ----
    if (tid < 128) {
        float h = 0.f;
        #pragma unroll
        for (int i = 0; i < LOOK; i++) {          // lookback rows 0..15
            int row = r0 - LOOK + i;
            float ca = us2f(SCA[i * CSTR + tid]);
            float cb = us2f(SCB[i * CSTR + tid]);
            h = (row >= 0) ? fmaf(ca, h, cb) : 0.f;
        }
        #pragma unroll 8
        for (int i = LOOK; i < LOOK + 40; i++) {  // output rows 16..55
            float ca = us2f(SCA[i * CSTR + tid]);
            float cb = us2f(SCB[i * CSTR + tid]);
            h = fmaf(ca, h, cb);
            SCA[i * CSTR + tid] = f2us(h);        // same thread, same address
        }
    } else {
        float h = 0.f;
        #pragma unroll
        for (int i = 0; i < LOOK; i++)            // reg-cached lookback 40..55
            h = fmaf(lca[i], h, lcb[i]);
        #pragma unroll 8
        for (int i = 56; i < 96; i++) {           // output rows 56..95
            float ca = us2f(SCA[i * CSTR + dmm]);
            float cb = us2f(SCB[i * CSTR + dmm]);
            h = fmaf(ca, h, cb);
            SCA[i * CSTR + dmm] = f2us(h);
        }
    }
    __syncthreads();

    // ---- phase 3: per 16-row tile: y = x + h@Wo + bo, LayerNorm, store ----
    bf8 b0[4], b1[4];
    #pragma unroll
    for (int kb = 0; kb < 4; kb++) {
        int ko = kb * 32 + quad * 8;
        b0[kb] = *(const bf8*)(WoT + (size_t)cz0 * 128 + ko);
        b1[kb] = *(const bf8*)(WoT + (size_t)cz1 * 128 + ko);
    }
    float bias0 = bo[cz0], bias1 = bo[cz1];
    float gl0 = lg[cz0], gl1 = lg[cz1], bl0 = lb[cz0], bl1 = lb[cz1];

    for (int rt = 0; rt < RB / 16; rt++) {
        bf8 a[4];
        #pragma unroll
        for (int kb = 0; kb < 4; kb++)
            a[kb] = *(const bf8*)(SCA + (LOOK + rt * 16 + m) * CSTR
                                      + kb * 32 + quad * 8);
        f32x4 acc0 = {0.f, 0.f, 0.f, 0.f}, acc1 = acc0;
        #pragma unroll
        for (int kb = 0; kb < 4; kb++) {
            acc0 = __builtin_amdgcn_mfma_f32_16x16x32_bf16(a[kb], b0[kb], acc0, 0, 0, 0);
            acc1 = __builtin_amdgcn_mfma_f32_16x16x32_bf16(a[kb], b1[kb], acc1, 0, 0, 0);
        }
        float y0[4], y1[4];
        #pragma unroll
        for (int reg = 0; reg < 4; reg++) {
            int gr = r0 + rt * 16 + quad * 4 + reg;
            y0[reg] = acc0[reg] + bias0 + us2f(xin[(size_t)gr * 128 + cz0]);
            y1[reg] = acc1[reg] + bias1 + us2f(xin[(size_t)gr * 128 + cz1]);
        }
        #pragma unroll
        for (int reg = 0; reg < 4; reg++) {
            float v0 = y0[reg], v1 = y1[reg];
            float s = v0 + v1, q = v0 * v0 + v1 * v1;
            #pragma unroll
            for (int mk = 1; mk <= 8; mk <<= 1) {
                s += __shfl_xor(s, mk, 64);
                q += __shfl_xor(q, mk, 64);
            }
            if (m == 0) {
                int row = quad * 4 + reg;
                redS[row * 4 + w] = s;
                redQ[row * 4 + w] = q;
            }
        }
        __syncthreads();
        if (tid < 16) {
            float s = redS[tid * 4] + redS[tid * 4 + 1] + redS[tid * 4 + 2] + redS[tid * 4 + 3];
            float q = redQ[tid * 4] + redQ[tid * 4 + 1] + redQ[tid * 4 + 2] + redQ[tid * 4 + 3];
            float mu = s * (1.f / 128.f);
            float var = q * (1.f / 128.f) - mu * mu;
            muA[tid] = mu;
            rsA[tid] = rsqrtf(var + 1e-5f);
        }
        __syncthreads();
        #pragma unroll
        for (int reg = 0; reg < 4; reg++) {
            int rr = quad * 4 + reg;
            int gr = r0 + rt * 16 + rr;
            float mu = muA[rr], rs = rsA[rr];
            float v0 = (y0[reg] - mu) * rs * gl0 + bl0;
            float v1 = (y1[reg] - mu) * rs * gl1 + bl1;
            if (FINAL) {
                outf[(size_t)gr * 128 + cz0] = v0;
                outf[(size_t)gr * 128 + cz1] = v1;
            } else {
                xoutb[(size_t)gr * 128 + cz0] = f2us(v0);
                xoutb[(size_t)gr * 128 + cz1] = f2us(v1);
            }
        }
        // redS/redQ reuse is safe: writers of the next tile pass this tile's
        // second barrier before its readers (tid<16) could be outrun.
    }
}

extern "C" void kernel_launch(void* const* d_in, const int* in_sizes, int n_in,
                              void* d_out, int out_size, void* d_ws, size_t ws_size,
                              hipStream_t stream)
{
    const int*   eidx  = (const int*)d_in[0];
    const int*   etype = (const int*)d_in[1];
    const int*   etime = (const int*)d_in[2];
    const float* ew    = (const float*)d_in[3];
    const int*   perm  = (const int*)d_in[4];
    const float* ent   = (const float*)d_in[5];
    const float* rel   = (const float*)d_in[6];
    const float* tim   = (const float*)d_in[7];
    const float* Wi    = (const float*)d_in[8];
    const float* bi    = (const float*)d_in[9];
    const float* Wo    = (const float*)d_in[10];
    const float* bo    = (const float*)d_in[11];
    const float* Aw    = (const float*)d_in[12];
    const float* Bw    = (const float*)d_in[13];
    const float* lg    = (const float*)d_in[14];
    const float* lbp   = (const float*)d_in[15];

    char* base = (char*)d_ws;
    size_t o = 0;
    ushort_t* xbf  = (ushort_t*)(base + o); o += (size_t)N * D * 2;
    ushort_t* xb2  = (ushort_t*)(base + o); o += (size_t)N * D * 2;
    ushort_t* entb = (ushort_t*)(base + o); o += (size_t)N * D * 2;
    ushort_t* relb = (ushort_t*)(base + o); o += (size_t)200 * D * 2;
    ushort_t* timb = (ushort_t*)(base + o); o += (size_t)1000 * D * 2;
    ushort_t* WiT  = (ushort_t*)(base + o); o += (size_t)L * 256 * 128 * 2;
    ushort_t* WoT  = (ushort_t*)(base + o); o += (size_t)L * 128 * 128 * 2;
    int2*     esort  = (int2*)(base + o);   o += (size_t)E * 8;
    int*      hist   = (int*)(base + o);    o += (size_t)N * 4;
    int*      gcnt   = (int*)(base + o);    o += 4;              // adjacent: one memset
    int*      cursor = (int*)(base + o);    o += (size_t)N * 4;
    int*      rowst  = (int*)(base + o);    o += (size_t)N * 4;
    int*      invp   = (int*)(base + o);    o += (size_t)N * 4;

    hipMemsetAsync(hist, 0, (N + 1) * sizeof(int), stream);   // hist + gcnt

    k_cast    <<<(int)((CAST_TOT + 255) / 256), 256, 0, stream>>>(
                  ent, rel, tim, Wi, Wo, eidx + E, perm,
                  entb, relb, timb, WiT, WoT, hist, invp);
    k_alloc   <<<NB, 256, 0, stream>>>(hist, gcnt, cursor, rowst);
    k_scatter <<<(E + 255) / 256, 256, 0, stream>>>(eidx, etype, etime, ew,
                                                    cursor, esort);
    k_agg     <<<(N + 3) / 4, 256, 0, stream>>>(esort, rowst, hist, invp,
                                                entb, relb, timb, xbf);

    k_layer<false><<<RBLK, 256, 0, stream>>>(
        xbf, WiT, bi, WoT, bo, Aw, Bw, lg, lbp, xb2, nullptr);
    k_layer<true><<<RBLK, 256, 0, stream>>>(
        xb2, WiT + (size_t)256 * 128, bi + 256, WoT + (size_t)128 * 128,
        bo + 128, Aw + 128, Bw + 128, lg + 128, lbp + 128,
        nullptr, (float*)d_out);
}